// Round 1
// baseline (643.365 us; speedup 1.0000x reference)
//
#include <hip/hip_runtime.h>

// PFCAttention on MI355X (gfx950).
// Shapes: B=16, H=W=64, C=512, WS=8 -> N=64 tok/window, nWs=64, B_=1024, NH=16, hd=32.
// Faithful-bug note: windows are consecutive 64-row chunks of the row-major (B*H*W, C)
// activation, so QKV is a plain GEMM and window b_ = row/64, token n = row%64.
//
// Fusion: out = fineA @ (Lw@Ptop) + coarseA @ (Gw@Pbot) + (lpb@Ptop + gpb@Pbot + pfc_b)
// -> precompute Wc (1024x512) once per call; deletes local_proj/global_proj GEMMs.
//
// All matmuls use fp16 MFMA (v_mfma_f32_16x16x32_f16), fp32 accumulate.
//
// Workspace layout (bytes), total 340,789,248 (~326 MB):
//   qb   @ 0          (64 MiB)  fp16 [B_*NH][64][32]
//   kb   @ 67108864   (64 MiB)
//   vb   @ 134217728  (64 MiB)
//   cat  @ 201326592  (128 MiB) fp16 [65536][1024]  (fine | coarse)
//   qwT  @ 335544320  (1.5 MiB) fp16 [1536][512]   qkv_w transposed
//   WcT  @ 337117184  (1 MiB)   fp16 [512][1024]   combined proj, transposed
//   bc   @ 338165760  (2 KiB)   fp32 [512]
//   lbf  @ 338167808  (256 KiB) fp32 [16][64][64]
//   gbf  @ 338429952  (256 KiB) fp32 [16][64][64]
//   Kgb  @ 338692096  (1 MiB)   fp16 [B*NH][64][32]  pooled K
//   Vgt  @ 339740672  (1 MiB)   fp16 [B*NH][32][64]  pooled V, transposed

typedef unsigned int u32;
typedef _Float16 f16;
typedef __attribute__((ext_vector_type(8))) _Float16 f16x8;
typedef __attribute__((ext_vector_type(4))) float f32x4;

__device__ __forceinline__ f32x4 mfma_16x16x32(f16x8 a, f16x8 b, f32x4 c) {
  return __builtin_amdgcn_mfma_f32_16x16x32_f16(a, b, c, 0, 0, 0);
}

__device__ __forceinline__ void async_cp16(const void* g, void* l) {
  __builtin_amdgcn_global_load_lds(
      (const __attribute__((address_space(1))) u32*)g,
      (__attribute__((address_space(3))) u32*)l, 16, 0, 0);
}

__device__ __forceinline__ f16x8 cvt8(const float4 a, const float4 b) {
  f16x8 r;
  r[0] = (f16)a.x; r[1] = (f16)a.y; r[2] = (f16)a.z; r[3] = (f16)a.w;
  r[4] = (f16)b.x; r[5] = (f16)b.y; r[6] = (f16)b.z; r[7] = (f16)b.w;
  return r;
}

// ---------------------------------------------------------------------------
// Prep kernels
// ---------------------------------------------------------------------------

// lbf[h][n][m], gbf[h][n][w] gathered bias tables (fp32). grid 32 x 256.
__global__ void k_biastab(const float* __restrict__ ltab, const float* __restrict__ gtab,
                          float* __restrict__ lbf, float* __restrict__ gbf) {
  const int id = blockIdx.x * 256 + threadIdx.x;   // 0..8191
  const int pair = id & 4095;
  const int n = pair >> 6, m = pair & 63;
  const int yn = n >> 3, xn = n & 7;
  const int ym = m >> 3, xm = m & 7;               // m = key token OR window index
  const int idx = (yn - ym + 7) * 15 + (xn - xm + 7);
  if (id < 4096) {
#pragma unroll
    for (int h = 0; h < 16; ++h) lbf[h * 4096 + pair] = ltab[idx * 16 + h];
  } else {
#pragma unroll
    for (int h = 0; h < 16; ++h) gbf[h * 4096 + pair] = gtab[idx * 16 + h];
  }
}

// qkv_w (512x1536 fp32) -> qwT (1536x512 fp16). grid 3072 x 256, coalesced read.
__global__ void k_tqkvw(const float* __restrict__ w, f16* __restrict__ wT) {
  const int id = blockIdx.x * 256 + threadIdx.x;   // 0..786431
  const int k = id / 1536, n = id % 1536;
  wT[n * 512 + k] = (f16)w[id];
}

// WcT[j][kk] = sum_c proj[kk][c] * pfc[c(+512)][j]. grid 64 blocks (16 kk each), 256 thr.
__global__ __launch_bounds__(256) void k_compose(const float* __restrict__ lpw,
                                                 const float* __restrict__ gpw,
                                                 const float* __restrict__ pfc_w,
                                                 f16* __restrict__ WT) {
  __shared__ float sW[16][16];
  const int kk0 = blockIdx.x * 16;
  const bool top = kk0 < 512;
  const float* src = top ? (lpw + kk0 * 512) : (gpw + (kk0 - 512) * 512);
  const float* pf = pfc_w + (top ? 0 : 512 * 512);
  const int t = threadIdx.x;
  float acc0[16], acc1[16];
#pragma unroll
  for (int i = 0; i < 16; ++i) { acc0[i] = 0.f; acc1[i] = 0.f; }
  for (int ct = 0; ct < 32; ++ct) {
    sW[t >> 4][t & 15] = src[(t >> 4) * 512 + ct * 16 + (t & 15)];
    __syncthreads();
#pragma unroll
    for (int cc = 0; cc < 16; ++cc) {
      const int c = ct * 16 + cc;
      const float p0 = pf[c * 512 + t];
      const float p1 = pf[c * 512 + t + 256];
#pragma unroll
      for (int i = 0; i < 16; ++i) { acc0[i] += sW[i][cc] * p0; acc1[i] += sW[i][cc] * p1; }
    }
    __syncthreads();
  }
#pragma unroll
  for (int i = 0; i < 16; ++i) WT[(size_t)t * 1024 + kk0 + i] = (f16)acc0[i];
#pragma unroll
  for (int i = 0; i < 16; ++i) WT[(size_t)(t + 256) * 1024 + kk0 + i] = (f16)acc1[i];
}

// bc[j] = sum_c lpb[c]*pfc[c][j] + gpb[c]*pfc[512+c][j] + pfc_b[j]. grid 2 x 256.
__global__ void k_bc(const float* __restrict__ lpb, const float* __restrict__ gpb,
                     const float* __restrict__ pfc_w, const float* __restrict__ pfc_b,
                     float* __restrict__ bc) {
  const int j = blockIdx.x * 256 + threadIdx.x;
  float acc = pfc_b[j];
  for (int c = 0; c < 512; ++c)
    acc += lpb[c] * pfc_w[c * 512 + j] + gpb[c] * pfc_w[(512 + c) * 512 + j];
  bc[j] = acc;
}

// ---------------------------------------------------------------------------
// QKV GEMM: (65536x512 fp32) @ qwT^T -> q/k/v fp16 in [B_*NH][64][32] layout.
// 128x128x32 tile, m97-style 2-barrier loop. grid 6144 (br*12+bn) x 256.
// ---------------------------------------------------------------------------
__global__ __launch_bounds__(256) void k_gemm_qkv(const float* __restrict__ X,
                                                  const f16* __restrict__ BT,
                                                  const float* __restrict__ qkv_b,
                                                  f16* __restrict__ qb,
                                                  f16* __restrict__ kb,
                                                  f16* __restrict__ vb) {
  __shared__ f16 sA[4096], sB[4096];
  const int bid = blockIdx.x;
  const int br = bid / 12, bn = bid % 12;
  const int t = threadIdx.x;
  const int wv = t >> 6, l = t & 63, lr = l & 15, lk = l >> 4;
  const int wr = (wv & 1) * 64, wc = (wv >> 1) * 64;

  f32x4 acc[4][4] = {};

  const float* gA = X + (size_t)(br * 128 + (t >> 1)) * 512 + (t & 1) * 16;
  const f16* gB0 = BT + (size_t)(bn * 128 + (t >> 2)) * 512 + (t & 3) * 8;
  const f16* gB1 = gB0 + 64 * 512;

  for (int kk = 0; kk < 16; ++kk) {
    async_cp16(gB0 + kk * 32, &sB[t * 8]);
    async_cp16(gB1 + kk * 32, &sB[2048 + t * 8]);
    const float4 a0 = *reinterpret_cast<const float4*>(gA + kk * 32);
    const float4 a1 = *reinterpret_cast<const float4*>(gA + kk * 32 + 4);
    const float4 a2 = *reinterpret_cast<const float4*>(gA + kk * 32 + 8);
    const float4 a3 = *reinterpret_cast<const float4*>(gA + kk * 32 + 12);
    *reinterpret_cast<f16x8*>(&sA[t * 16]) = cvt8(a0, a1);
    *reinterpret_cast<f16x8*>(&sA[t * 16 + 8]) = cvt8(a2, a3);
    __syncthreads();
    f16x8 af[4], bf[4];
#pragma unroll
    for (int m = 0; m < 4; ++m)
      af[m] = *reinterpret_cast<const f16x8*>(&sA[(wr + m * 16 + lr) * 32 + lk * 8]);
#pragma unroll
    for (int n = 0; n < 4; ++n)
      bf[n] = *reinterpret_cast<const f16x8*>(&sB[(wc + n * 16 + lr) * 32 + lk * 8]);
#pragma unroll
    for (int m = 0; m < 4; ++m)
#pragma unroll
      for (int n = 0; n < 4; ++n) acc[m][n] = mfma_16x16x32(af[m], bf[n], acc[m][n]);
    __syncthreads();
  }

#pragma unroll
  for (int n = 0; n < 4; ++n) {
    const int col = bn * 128 + wc + n * 16 + lr;         // 0..1535
    const int which = col >> 9;
    const int hh = (col >> 5) & 15;
    const int d = col & 31;
    f16* dst = which == 0 ? qb : (which == 1 ? kb : vb);
    const float bias = qkv_b[col];
#pragma unroll
    for (int m = 0; m < 4; ++m)
#pragma unroll
      for (int r = 0; r < 4; ++r) {
        const int row = br * 128 + wr + m * 16 + lk * 4 + r;   // 0..65535
        dst[(size_t)(((row >> 6) << 4) + hh) * 2048 + (row & 63) * 32 + d] =
            (f16)(acc[m][n][r] + bias);
      }
  }
}

// ---------------------------------------------------------------------------
// Pooling: Kg[b][h][w][d] = sum_n k[b_,h,n,d]*pool_w[n] + pool_b (same for V).
// Kgb row-major [w][32]; Vgt transposed [32][64]. grid 16384 (=(b*16+h)*64+w) x 64.
// ---------------------------------------------------------------------------
__global__ void k_pool(const f16* __restrict__ kb, const f16* __restrict__ vb,
                       const float* __restrict__ pool_w, const float* __restrict__ pool_b,
                       f16* __restrict__ Kgb, f16* __restrict__ Vgt) {
  const int bid = blockIdx.x;
  const int w = bid & 63, h = (bid >> 6) & 15, b = bid >> 10;
  const int d = threadIdx.x & 31;
  const f16* src = (threadIdx.x < 32 ? kb : vb) + (size_t)((b * 64 + w) * 16 + h) * 2048;
  float acc = 0.f;
#pragma unroll 8
  for (int n = 0; n < 64; ++n) acc += (float)src[n * 32 + d] * pool_w[n];
  acc += pool_b[0];
  if (threadIdx.x < 32)
    Kgb[(size_t)bid * 32 + d] = (f16)acc;
  else
    Vgt[((size_t)(b * 16 + h) * 32 + d) * 64 + w] = (f16)acc;
}

// ---------------------------------------------------------------------------
// Attention: one block per (b_, h). 4 waves x 16-query-row strips.
// fine:  softmax(q k^T * scale + lb) v      -> cat[:, h*32+d]
// coarse: softmax(q Kg^T * scale + gb) Vg   -> cat[:, 512+h*32+d]
// ---------------------------------------------------------------------------
__device__ __forceinline__ void attn_half(const f16x8 aq, const f16* sKm, const f16* sVm,
                                          const float* __restrict__ btab, f16* sP,
                                          const int wv, const int lr, const int lk,
                                          f16* __restrict__ catp) {
  const float scale = 0.17677669529663687f;   // 1/sqrt(32)
  f32x4 s[4] = {};
#pragma unroll
  for (int j = 0; j < 4; ++j)
    s[j] = mfma_16x16x32(aq, *reinterpret_cast<const f16x8*>(&sKm[(j * 16 + lr) * 32 + lk * 8]), s[j]);

  const float* bt = btab + (wv * 16 + lk * 4) * 64;
  float p[4][4], inv[4];
#pragma unroll
  for (int r = 0; r < 4; ++r) {
    float m = -1e30f;
#pragma unroll
    for (int j = 0; j < 4; ++j) {
      const float v = s[j][r] * scale + bt[r * 64 + j * 16 + lr];
      p[j][r] = v;
      m = fmaxf(m, v);
    }
    m = fmaxf(m, __shfl_xor(m, 1));
    m = fmaxf(m, __shfl_xor(m, 2));
    m = fmaxf(m, __shfl_xor(m, 4));
    m = fmaxf(m, __shfl_xor(m, 8));
    float su = 0.f;
#pragma unroll
    for (int j = 0; j < 4; ++j) {
      const float e = __expf(p[j][r] - m);
      p[j][r] = e;
      su += e;
    }
    su += __shfl_xor(su, 1);
    su += __shfl_xor(su, 2);
    su += __shfl_xor(su, 4);
    su += __shfl_xor(su, 8);
    inv[r] = 1.f / su;
  }
  // unnormalized P -> LDS (wave touches only its own 16 rows)
#pragma unroll
  for (int r = 0; r < 4; ++r)
#pragma unroll
    for (int j = 0; j < 4; ++j)
      sP[(wv * 16 + lk * 4 + r) * 64 + j * 16 + lr] = (f16)p[j][r];

  const f16x8 a0 = *reinterpret_cast<const f16x8*>(&sP[(wv * 16 + lr) * 64 + lk * 8]);
  const f16x8 a1 = *reinterpret_cast<const f16x8*>(&sP[(wv * 16 + lr) * 64 + 32 + lk * 8]);
#pragma unroll
  for (int n = 0; n < 2; ++n) {
    f32x4 o = {};
    o = mfma_16x16x32(a0, *reinterpret_cast<const f16x8*>(&sVm[(n * 16 + lr) * 64 + lk * 8]), o);
    o = mfma_16x16x32(a1, *reinterpret_cast<const f16x8*>(&sVm[(n * 16 + lr) * 64 + 32 + lk * 8]), o);
#pragma unroll
    for (int r = 0; r < 4; ++r)
      catp[(size_t)(wv * 16 + lk * 4 + r) * 1024 + n * 16 + lr] = (f16)(o[r] * inv[r]);
  }
}

__global__ __launch_bounds__(256) void k_attn(const f16* __restrict__ qb,
                                              const f16* __restrict__ kb,
                                              const f16* __restrict__ vb,
                                              const f16* __restrict__ Kgb,
                                              const f16* __restrict__ Vgt,
                                              const float* __restrict__ lbf,
                                              const float* __restrict__ gbf,
                                              f16* __restrict__ cat) {
  __shared__ f16 sQ[2048], sK[2048], sVt[2048], sKg[2048], sVgt[2048], sP[4096];
  const int bid = blockIdx.x;          // b_*16 + h
  const int b_ = bid >> 4, h = bid & 15;
  const int gslice = ((b_ >> 6) << 4) + h;   // b*16 + h
  const int t = threadIdx.x;
  const int wv = t >> 6, l = t & 63, lr = l & 15, lk = l >> 4;

  async_cp16(qb + (size_t)bid * 2048 + t * 8, &sQ[t * 8]);
  async_cp16(kb + (size_t)bid * 2048 + t * 8, &sK[t * 8]);
  async_cp16(vb + (size_t)bid * 2048 + t * 8, &sP[t * 8]);   // V staged into sP temp
  async_cp16(Kgb + (size_t)gslice * 2048 + t * 8, &sKg[t * 8]);
  async_cp16(Vgt + (size_t)gslice * 2048 + t * 8, &sVgt[t * 8]);
  __syncthreads();

  // transpose V: sP[64][32] -> sVt[32][64]
  {
    const int d = t >> 3, n0 = (t & 7) << 3;
    f16x8 wr;
#pragma unroll
    for (int j = 0; j < 8; ++j) wr[j] = sP[(n0 + j) * 32 + d];
    *reinterpret_cast<f16x8*>(&sVt[d * 64 + n0]) = wr;
  }
  __syncthreads();

  const f16x8 aq = *reinterpret_cast<const f16x8*>(&sQ[(wv * 16 + lr) * 32 + lk * 8]);
  f16* catp = cat + (size_t)b_ * 64 * 1024 + h * 32;

  attn_half(aq, sK, sVt, lbf + h * 4096, sP, wv, lr, lk, catp);          // fine
  attn_half(aq, sKg, sVgt, gbf + h * 4096, sP, wv, lr, lk, catp + 512);  // coarse
}

// ---------------------------------------------------------------------------
// Final GEMM: out(65536x512 fp32) = cat(65536x1024 f16) @ WcT^T + bc
// grid 2048 (br*4+bn) x 256.
// ---------------------------------------------------------------------------
__global__ __launch_bounds__(256) void k_gemm_final(const f16* __restrict__ A,
                                                    const f16* __restrict__ BT,
                                                    const float* __restrict__ bc,
                                                    float* __restrict__ out) {
  __shared__ f16 sA[4096], sB[4096];
  const int bid = blockIdx.x;
  const int br = bid >> 2, bn = bid & 3;
  const int t = threadIdx.x;
  const int wv = t >> 6, l = t & 63, lr = l & 15, lk = l >> 4;
  const int wr = (wv & 1) * 64, wc = (wv >> 1) * 64;

  f32x4 acc[4][4] = {};

  const f16* gA0 = A + (size_t)(br * 128 + (t >> 2)) * 1024 + (t & 3) * 8;
  const f16* gA1 = gA0 + (size_t)64 * 1024;
  const f16* gB0 = BT + (size_t)(bn * 128 + (t >> 2)) * 1024 + (t & 3) * 8;
  const f16* gB1 = gB0 + (size_t)64 * 1024;

  for (int kk = 0; kk < 32; ++kk) {
    async_cp16(gA0 + kk * 32, &sA[t * 8]);
    async_cp16(gA1 + kk * 32, &sA[2048 + t * 8]);
    async_cp16(gB0 + kk * 32, &sB[t * 8]);
    async_cp16(gB1 + kk * 32, &sB[2048 + t * 8]);
    __syncthreads();
    f16x8 af[4], bf[4];
#pragma unroll
    for (int m = 0; m < 4; ++m)
      af[m] = *reinterpret_cast<const f16x8*>(&sA[(wr + m * 16 + lr) * 32 + lk * 8]);
#pragma unroll
    for (int n = 0; n < 4; ++n)
      bf[n] = *reinterpret_cast<const f16x8*>(&sB[(wc + n * 16 + lr) * 32 + lk * 8]);
#pragma unroll
    for (int m = 0; m < 4; ++m)
#pragma unroll
      for (int n = 0; n < 4; ++n) acc[m][n] = mfma_16x16x32(af[m], bf[n], acc[m][n]);
    __syncthreads();
  }

#pragma unroll
  for (int n = 0; n < 4; ++n) {
    const int col = bn * 128 + wc + n * 16 + lr;
    const float bias = bc[col];
#pragma unroll
    for (int m = 0; m < 4; ++m)
#pragma unroll
      for (int r = 0; r < 4; ++r) {
        const int row = br * 128 + wr + m * 16 + lk * 4 + r;
        out[(size_t)row * 512 + col] = acc[m][n][r] + bias;
      }
  }
}

// ---------------------------------------------------------------------------

extern "C" void kernel_launch(void* const* d_in, const int* in_sizes, int n_in,
                              void* d_out, int out_size, void* d_ws, size_t ws_size,
                              hipStream_t stream) {
  const float* x      = (const float*)d_in[0];
  const float* qkv_w  = (const float*)d_in[1];
  const float* qkv_b  = (const float*)d_in[2];
  const float* ltab   = (const float*)d_in[3];
  const float* gtab   = (const float*)d_in[4];
  const float* lpw    = (const float*)d_in[5];
  const float* lpb    = (const float*)d_in[6];
  const float* pool_w = (const float*)d_in[7];
  const float* pool_b = (const float*)d_in[8];
  const float* gpw    = (const float*)d_in[9];
  const float* gpb    = (const float*)d_in[10];
  const float* pfc_w  = (const float*)d_in[11];
  const float* pfc_b  = (const float*)d_in[12];
  float* out = (float*)d_out;

  char* ws = (char*)d_ws;
  f16*   qb   = (f16*)(ws + 0);
  f16*   kb   = (f16*)(ws + 67108864);
  f16*   vb   = (f16*)(ws + 134217728);
  f16*   cat  = (f16*)(ws + 201326592);
  f16*   qwT  = (f16*)(ws + 335544320);
  f16*   WcT  = (f16*)(ws + 337117184);
  float* bc   = (float*)(ws + 338165760);
  float* lbf  = (float*)(ws + 338167808);
  float* gbf  = (float*)(ws + 338429952);
  f16*   Kgb  = (f16*)(ws + 338692096);
  f16*   Vgt  = (f16*)(ws + 339740672);
  // total ws need: 340,789,248 bytes

  k_biastab<<<32, 256, 0, stream>>>(ltab, gtab, lbf, gbf);
  k_tqkvw<<<3072, 256, 0, stream>>>(qkv_w, qwT);
  k_compose<<<64, 256, 0, stream>>>(lpw, gpw, pfc_w, WcT);
  k_bc<<<2, 256, 0, stream>>>(lpb, gpb, pfc_w, pfc_b, bc);
  k_gemm_qkv<<<6144, 256, 0, stream>>>(x, qwT, qkv_b, qb, kb, vb);
  k_pool<<<16384, 64, 0, stream>>>(kb, vb, pool_w, pool_b, Kgb, Vgt);
  k_attn<<<16384, 256, 0, stream>>>(qb, kb, vb, Kgb, Vgt, lbf, gbf, cat);
  k_gemm_final<<<2048, 256, 0, stream>>>(cat, WcT, bc, out);
}

// Round 2
// 533.767 us; speedup vs baseline: 1.2053x; 1.2053x over previous
//
#include <hip/hip_runtime.h>

// PFCAttention on MI355X (gfx950). Round 2.
// Shapes: B=16, H=W=64, C=512, WS=8 -> N=64 tok/window, nWs=64, B_=1024, NH=16, hd=32.
//
// Round-2 changes vs round 1:
//  - k_cvtx: X fp32 -> fp16 once; QKV GEMM stages A via global_load_lds (no VALU cvt).
//  - Both big GEMMs: 256x128 tiles, 8 waves, XCD-chunked swizzle (fixes 4x A over-fetch).
//  - k_tqkvw: LDS-tiled transpose (was 2B scattered writes).
//  - k_bc: 32-block atomic reduction (was 2 blocks x 512 serial iters).
//
// Workspace layout (bytes), total ~341 MB (X16 overlaps cat; disjoint lifetimes):
//   qb   @ 0          (64 MiB)  fp16 [B_*NH][64][32]
//   kb   @ 67108864   (64 MiB)
//   vb   @ 134217728  (64 MiB)
//   cat  @ 201326592  (128 MiB) fp16 [65536][1024]   (also X16 fp16 [65536][512] early)
//   qwT  @ 335544320  (1.5 MiB) fp16 [1536][512]
//   WcT  @ 337117184  (1 MiB)   fp16 [512][1024]
//   bc   @ 338165760  (2 KiB)   fp32 [512]  (includes pfc_b)
//   lbf  @ 338167808  (256 KiB) fp32 [16][64][64]
//   gbf  @ 338429952  (256 KiB) fp32 [16][64][64]
//   Kgb  @ 338692096  (1 MiB)   fp16 [B*NH][64][32]
//   Vgt  @ 339740672  (1 MiB)   fp16 [B*NH][32][64]

typedef unsigned int u32;
typedef _Float16 f16;
typedef __attribute__((ext_vector_type(8))) _Float16 f16x8;
typedef __attribute__((ext_vector_type(4))) float f32x4;

__device__ __forceinline__ f32x4 mfma_16x16x32(f16x8 a, f16x8 b, f32x4 c) {
  return __builtin_amdgcn_mfma_f32_16x16x32_f16(a, b, c, 0, 0, 0);
}

__device__ __forceinline__ void async_cp16(const void* g, void* l) {
  __builtin_amdgcn_global_load_lds(
      (const __attribute__((address_space(1))) u32*)g,
      (__attribute__((address_space(3))) u32*)l, 16, 0, 0);
}

// ---------------------------------------------------------------------------
// Prep kernels
// ---------------------------------------------------------------------------

// X (65536x512 fp32) -> X16 fp16. grid 2048 x 256, 8 elems/thread/iter, 8 iters.
__global__ void k_cvtx(const float* __restrict__ X, f16* __restrict__ X16) {
  const size_t stride = (size_t)2048 * 256 * 8;
  size_t base = ((size_t)blockIdx.x * 256 + threadIdx.x) * 8;
  for (int it = 0; it < 8; ++it, base += stride) {
    const float4 a = *reinterpret_cast<const float4*>(X + base);
    const float4 b = *reinterpret_cast<const float4*>(X + base + 4);
    f16x8 r;
    r[0] = (f16)a.x; r[1] = (f16)a.y; r[2] = (f16)a.z; r[3] = (f16)a.w;
    r[4] = (f16)b.x; r[5] = (f16)b.y; r[6] = (f16)b.z; r[7] = (f16)b.w;
    *reinterpret_cast<f16x8*>(X16 + base) = r;
  }
}

// lbf[h][n][m], gbf[h][n][w] gathered bias tables (fp32). grid 32 x 256.
__global__ void k_biastab(const float* __restrict__ ltab, const float* __restrict__ gtab,
                          float* __restrict__ lbf, float* __restrict__ gbf) {
  const int id = blockIdx.x * 256 + threadIdx.x;   // 0..8191
  const int pair = id & 4095;
  const int n = pair >> 6, m = pair & 63;
  const int yn = n >> 3, xn = n & 7;
  const int ym = m >> 3, xm = m & 7;
  const int idx = (yn - ym + 7) * 15 + (xn - xm + 7);
  if (id < 4096) {
#pragma unroll
    for (int h = 0; h < 16; ++h) lbf[h * 4096 + pair] = ltab[idx * 16 + h];
  } else {
#pragma unroll
    for (int h = 0; h < 16; ++h) gbf[h * 4096 + pair] = gtab[idx * 16 + h];
  }
}

// qkv_w (512x1536 fp32) -> qwT (1536x512 fp16), LDS-tiled 64x64. grid 192 x 256.
__global__ void k_tqkvw(const float* __restrict__ w, f16* __restrict__ wT) {
  __shared__ f16 sT[64][72];
  const int bid = blockIdx.x;
  const int k0 = (bid / 24) * 64, n0 = (bid % 24) * 64;
  const int t = threadIdx.x;
  // load: 4 passes, 16 k-rows x (16 thr x float4) each
#pragma unroll
  for (int p = 0; p < 4; ++p) {
    const int kl = p * 16 + (t >> 4), nl = (t & 15) * 4;
    const float4 v = *reinterpret_cast<const float4*>(w + (size_t)(k0 + kl) * 1536 + n0 + nl);
    sT[kl][nl] = (f16)v.x; sT[kl][nl + 1] = (f16)v.y;
    sT[kl][nl + 2] = (f16)v.z; sT[kl][nl + 3] = (f16)v.w;
  }
  __syncthreads();
  // store: 2 passes, 32 n-rows x (8 thr x f16x8) each
#pragma unroll
  for (int q = 0; q < 2; ++q) {
    const int nl = q * 32 + (t >> 3), kl = (t & 7) * 8;
    f16x8 r;
#pragma unroll
    for (int j = 0; j < 8; ++j) r[j] = sT[kl + j][nl];
    *reinterpret_cast<f16x8*>(wT + (size_t)(n0 + nl) * 512 + k0 + kl) = r;
  }
}

// WcT[j][kk] = sum_c proj[kk][c] * pfc[c(+512)][j]. grid 64 blocks, 256 thr.
__global__ __launch_bounds__(256) void k_compose(const float* __restrict__ lpw,
                                                 const float* __restrict__ gpw,
                                                 const float* __restrict__ pfc_w,
                                                 f16* __restrict__ WT) {
  __shared__ float sW[16][16];
  const int kk0 = blockIdx.x * 16;
  const bool top = kk0 < 512;
  const float* src = top ? (lpw + kk0 * 512) : (gpw + (kk0 - 512) * 512);
  const float* pf = pfc_w + (top ? 0 : 512 * 512);
  const int t = threadIdx.x;
  float acc0[16], acc1[16];
#pragma unroll
  for (int i = 0; i < 16; ++i) { acc0[i] = 0.f; acc1[i] = 0.f; }
  for (int ct = 0; ct < 32; ++ct) {
    sW[t >> 4][t & 15] = src[(t >> 4) * 512 + ct * 16 + (t & 15)];
    __syncthreads();
#pragma unroll
    for (int cc = 0; cc < 16; ++cc) {
      const int c = ct * 16 + cc;
      const float p0 = pf[c * 512 + t];
      const float p1 = pf[c * 512 + t + 256];
#pragma unroll
      for (int i = 0; i < 16; ++i) { acc0[i] += sW[i][cc] * p0; acc1[i] += sW[i][cc] * p1; }
    }
    __syncthreads();
  }
#pragma unroll
  for (int i = 0; i < 16; ++i) WT[(size_t)t * 1024 + kk0 + i] = (f16)acc0[i];
#pragma unroll
  for (int i = 0; i < 16; ++i) WT[(size_t)(t + 256) * 1024 + kk0 + i] = (f16)acc1[i];
}

// bc[j] = pfc_b[j]  (init).  grid 2 x 256.
__global__ void k_bc_init(const float* __restrict__ pfc_b, float* __restrict__ bc) {
  const int j = blockIdx.x * 256 + threadIdx.x;
  bc[j] = pfc_b[j];
}

// bc[j] += sum_c wgt(c) * pfc_w[c*512+j]; 32 blocks x 32 c-values each.
__global__ void k_bc_acc(const float* __restrict__ lpb, const float* __restrict__ gpb,
                         const float* __restrict__ pfc_w, float* __restrict__ bc) {
  const int t = threadIdx.x;
  const int c0 = blockIdx.x * 32;
  float p0 = 0.f, p1 = 0.f;
#pragma unroll
  for (int i = 0; i < 32; ++i) {
    const int c = c0 + i;
    const float wgt = (c < 512) ? lpb[c] : gpb[c - 512];
    p0 += wgt * pfc_w[(size_t)c * 512 + t];
    p1 += wgt * pfc_w[(size_t)c * 512 + t + 256];
  }
  atomicAdd(bc + t, p0);
  atomicAdd(bc + t + 256, p1);
}

// ---------------------------------------------------------------------------
// QKV GEMM: X16(65536x512 f16) @ qwT^T -> q/k/v f16 [B_*NH][64][32].
// 256x128 tile, 8 waves (4r x 2c), K-step 32, XCD-chunked swizzle. grid 3072 x 512.
// ---------------------------------------------------------------------------
__global__ __launch_bounds__(512) void k_gemm_qkv(const f16* __restrict__ A,
                                                  const f16* __restrict__ BT,
                                                  const float* __restrict__ qkv_b,
                                                  f16* __restrict__ qb,
                                                  f16* __restrict__ kb,
                                                  f16* __restrict__ vb) {
  __shared__ f16 sA[8192], sB[4096];
  const int wid = (blockIdx.x & 7) * 384 + (blockIdx.x >> 3);   // 3072/8 chunks
  const int br = wid / 12, bn = wid % 12;
  const int t = threadIdx.x;
  const int wv = t >> 6, l = t & 63, lr = l & 15, lk = l >> 4;
  const int wvr = wv >> 1, wvc = wv & 1;

  f32x4 acc[4][4] = {};

  const f16* gA = A + (size_t)(br * 256 + (t >> 2)) * 512 + (t & 3) * 8;
  const f16* gB = BT + (size_t)(bn * 128 + (t >> 2)) * 512 + (t & 3) * 8;

  for (int kk = 0; kk < 16; ++kk) {
    async_cp16(gA + kk * 32, &sA[t * 8]);
    async_cp16(gA + 128 * 512 + kk * 32, &sA[4096 + t * 8]);
    async_cp16(gB + kk * 32, &sB[t * 8]);
    __syncthreads();
    f16x8 af[4], bf[4];
#pragma unroll
    for (int m = 0; m < 4; ++m)
      af[m] = *reinterpret_cast<const f16x8*>(&sA[(wvr * 64 + m * 16 + lr) * 32 + lk * 8]);
#pragma unroll
    for (int n = 0; n < 4; ++n)
      bf[n] = *reinterpret_cast<const f16x8*>(&sB[(wvc * 64 + n * 16 + lr) * 32 + lk * 8]);
#pragma unroll
    for (int m = 0; m < 4; ++m)
#pragma unroll
      for (int n = 0; n < 4; ++n) acc[m][n] = mfma_16x16x32(af[m], bf[n], acc[m][n]);
    __syncthreads();
  }

#pragma unroll
  for (int n = 0; n < 4; ++n) {
    const int col = bn * 128 + wvc * 64 + n * 16 + lr;   // 0..1535
    const int which = col >> 9;
    const int hh = (col >> 5) & 15;
    const int d = col & 31;
    f16* dst = which == 0 ? qb : (which == 1 ? kb : vb);
    const float bias = qkv_b[col];
#pragma unroll
    for (int m = 0; m < 4; ++m)
#pragma unroll
      for (int r = 0; r < 4; ++r) {
        const int row = br * 256 + wvr * 64 + m * 16 + lk * 4 + r;
        dst[(size_t)(((row >> 6) << 4) + hh) * 2048 + (row & 63) * 32 + d] =
            (f16)(acc[m][n][r] + bias);
      }
  }
}

// ---------------------------------------------------------------------------
// Pooling. grid 16384 x 64.
// ---------------------------------------------------------------------------
__global__ void k_pool(const f16* __restrict__ kb, const f16* __restrict__ vb,
                       const float* __restrict__ pool_w, const float* __restrict__ pool_b,
                       f16* __restrict__ Kgb, f16* __restrict__ Vgt) {
  const int bid = blockIdx.x;
  const int w = bid & 63, h = (bid >> 6) & 15, b = bid >> 10;
  const int d = threadIdx.x & 31;
  const f16* src = (threadIdx.x < 32 ? kb : vb) + (size_t)((b * 64 + w) * 16 + h) * 2048;
  float acc = 0.f;
#pragma unroll 8
  for (int n = 0; n < 64; ++n) acc += (float)src[n * 32 + d] * pool_w[n];
  acc += pool_b[0];
  if (threadIdx.x < 32)
    Kgb[(size_t)bid * 32 + d] = (f16)acc;
  else
    Vgt[((size_t)(b * 16 + h) * 32 + d) * 64 + w] = (f16)acc;
}

// ---------------------------------------------------------------------------
// Attention: one block per (b_, h). 4 waves x 16-query-row strips.
// ---------------------------------------------------------------------------
__device__ __forceinline__ void attn_half(const f16x8 aq, const f16* sKm, const f16* sVm,
                                          const float* __restrict__ btab, f16* sP,
                                          const int wv, const int lr, const int lk,
                                          f16* __restrict__ catp) {
  const float scale = 0.17677669529663687f;   // 1/sqrt(32)
  f32x4 s[4] = {};
#pragma unroll
  for (int j = 0; j < 4; ++j)
    s[j] = mfma_16x16x32(aq, *reinterpret_cast<const f16x8*>(&sKm[(j * 16 + lr) * 32 + lk * 8]), s[j]);

  const float* bt = btab + (wv * 16 + lk * 4) * 64;
  float p[4][4], inv[4];
#pragma unroll
  for (int r = 0; r < 4; ++r) {
    float m = -1e30f;
#pragma unroll
    for (int j = 0; j < 4; ++j) {
      const float v = s[j][r] * scale + bt[r * 64 + j * 16 + lr];
      p[j][r] = v;
      m = fmaxf(m, v);
    }
    m = fmaxf(m, __shfl_xor(m, 1));
    m = fmaxf(m, __shfl_xor(m, 2));
    m = fmaxf(m, __shfl_xor(m, 4));
    m = fmaxf(m, __shfl_xor(m, 8));
    float su = 0.f;
#pragma unroll
    for (int j = 0; j < 4; ++j) {
      const float e = __expf(p[j][r] - m);
      p[j][r] = e;
      su += e;
    }
    su += __shfl_xor(su, 1);
    su += __shfl_xor(su, 2);
    su += __shfl_xor(su, 4);
    su += __shfl_xor(su, 8);
    inv[r] = 1.f / su;
  }
#pragma unroll
  for (int r = 0; r < 4; ++r)
#pragma unroll
    for (int j = 0; j < 4; ++j)
      sP[(wv * 16 + lk * 4 + r) * 64 + j * 16 + lr] = (f16)p[j][r];

  const f16x8 a0 = *reinterpret_cast<const f16x8*>(&sP[(wv * 16 + lr) * 64 + lk * 8]);
  const f16x8 a1 = *reinterpret_cast<const f16x8*>(&sP[(wv * 16 + lr) * 64 + 32 + lk * 8]);
#pragma unroll
  for (int n = 0; n < 2; ++n) {
    f32x4 o = {};
    o = mfma_16x16x32(a0, *reinterpret_cast<const f16x8*>(&sVm[(n * 16 + lr) * 64 + lk * 8]), o);
    o = mfma_16x16x32(a1, *reinterpret_cast<const f16x8*>(&sVm[(n * 16 + lr) * 64 + 32 + lk * 8]), o);
#pragma unroll
    for (int r = 0; r < 4; ++r)
      catp[(size_t)(wv * 16 + lk * 4 + r) * 1024 + n * 16 + lr] = (f16)(o[r] * inv[r]);
  }
}

__global__ __launch_bounds__(256) void k_attn(const f16* __restrict__ qb,
                                              const f16* __restrict__ kb,
                                              const f16* __restrict__ vb,
                                              const f16* __restrict__ Kgb,
                                              const f16* __restrict__ Vgt,
                                              const float* __restrict__ lbf,
                                              const float* __restrict__ gbf,
                                              f16* __restrict__ cat) {
  __shared__ f16 sQ[2048], sK[2048], sVt[2048], sKg[2048], sVgt[2048], sP[4096];
  const int bid = blockIdx.x;          // b_*16 + h
  const int b_ = bid >> 4, h = bid & 15;
  const int gslice = ((b_ >> 6) << 4) + h;   // b*16 + h
  const int t = threadIdx.x;
  const int wv = t >> 6, l = t & 63, lr = l & 15, lk = l >> 4;

  async_cp16(qb + (size_t)bid * 2048 + t * 8, &sQ[t * 8]);
  async_cp16(kb + (size_t)bid * 2048 + t * 8, &sK[t * 8]);
  async_cp16(vb + (size_t)bid * 2048 + t * 8, &sP[t * 8]);
  async_cp16(Kgb + (size_t)gslice * 2048 + t * 8, &sKg[t * 8]);
  async_cp16(Vgt + (size_t)gslice * 2048 + t * 8, &sVgt[t * 8]);
  __syncthreads();

  {
    const int d = t >> 3, n0 = (t & 7) << 3;
    f16x8 wr;
#pragma unroll
    for (int j = 0; j < 8; ++j) wr[j] = sP[(n0 + j) * 32 + d];
    *reinterpret_cast<f16x8*>(&sVt[d * 64 + n0]) = wr;
  }
  __syncthreads();

  const f16x8 aq = *reinterpret_cast<const f16x8*>(&sQ[(wv * 16 + lr) * 32 + lk * 8]);
  f16* catp = cat + (size_t)b_ * 64 * 1024 + h * 32;

  attn_half(aq, sK, sVt, lbf + h * 4096, sP, wv, lr, lk, catp);
  attn_half(aq, sKg, sVgt, gbf + h * 4096, sP, wv, lr, lk, catp + 512);
}

// ---------------------------------------------------------------------------
// Final GEMM: out(65536x512 fp32) = cat(65536x1024 f16) @ WcT^T + bc
// 256x128 tile, 8 waves, K-step 32, XCD-chunked swizzle. grid 1024 x 512.
// ---------------------------------------------------------------------------
__global__ __launch_bounds__(512) void k_gemm_final(const f16* __restrict__ A,
                                                    const f16* __restrict__ BT,
                                                    const float* __restrict__ bc,
                                                    float* __restrict__ out) {
  __shared__ f16 sA[8192], sB[4096];
  const int wid = (blockIdx.x & 7) * 128 + (blockIdx.x >> 3);   // 1024/8 chunks
  const int br = wid >> 2, bn = wid & 3;
  const int t = threadIdx.x;
  const int wv = t >> 6, l = t & 63, lr = l & 15, lk = l >> 4;
  const int wvr = wv >> 1, wvc = wv & 1;

  f32x4 acc[4][4] = {};

  const f16* gA = A + (size_t)(br * 256 + (t >> 2)) * 1024 + (t & 3) * 8;
  const f16* gB = BT + (size_t)(bn * 128 + (t >> 2)) * 1024 + (t & 3) * 8;

  for (int kk = 0; kk < 32; ++kk) {
    async_cp16(gA + kk * 32, &sA[t * 8]);
    async_cp16(gA + (size_t)128 * 1024 + kk * 32, &sA[4096 + t * 8]);
    async_cp16(gB + kk * 32, &sB[t * 8]);
    __syncthreads();
    f16x8 af[4], bf[4];
#pragma unroll
    for (int m = 0; m < 4; ++m)
      af[m] = *reinterpret_cast<const f16x8*>(&sA[(wvr * 64 + m * 16 + lr) * 32 + lk * 8]);
#pragma unroll
    for (int n = 0; n < 4; ++n)
      bf[n] = *reinterpret_cast<const f16x8*>(&sB[(wvc * 64 + n * 16 + lr) * 32 + lk * 8]);
#pragma unroll
    for (int m = 0; m < 4; ++m)
#pragma unroll
      for (int n = 0; n < 4; ++n) acc[m][n] = mfma_16x16x32(af[m], bf[n], acc[m][n]);
    __syncthreads();
  }

#pragma unroll
  for (int n = 0; n < 4; ++n) {
    const int col = bn * 128 + wvc * 64 + n * 16 + lr;
    const float bias = bc[col];
#pragma unroll
    for (int m = 0; m < 4; ++m)
#pragma unroll
      for (int r = 0; r < 4; ++r) {
        const int row = br * 256 + wvr * 64 + m * 16 + lk * 4 + r;
        out[(size_t)row * 512 + col] = acc[m][n][r] + bias;
      }
  }
}

// ---------------------------------------------------------------------------

extern "C" void kernel_launch(void* const* d_in, const int* in_sizes, int n_in,
                              void* d_out, int out_size, void* d_ws, size_t ws_size,
                              hipStream_t stream) {
  const float* x      = (const float*)d_in[0];
  const float* qkv_w  = (const float*)d_in[1];
  const float* qkv_b  = (const float*)d_in[2];
  const float* ltab   = (const float*)d_in[3];
  const float* gtab   = (const float*)d_in[4];
  const float* lpw    = (const float*)d_in[5];
  const float* lpb    = (const float*)d_in[6];
  const float* pool_w = (const float*)d_in[7];
  const float* pool_b = (const float*)d_in[8];
  const float* gpw    = (const float*)d_in[9];
  const float* gpb    = (const float*)d_in[10];
  const float* pfc_w  = (const float*)d_in[11];
  const float* pfc_b  = (const float*)d_in[12];
  float* out = (float*)d_out;

  char* ws = (char*)d_ws;
  f16*   qb   = (f16*)(ws + 0);
  f16*   kb   = (f16*)(ws + 67108864);
  f16*   vb   = (f16*)(ws + 134217728);
  f16*   cat  = (f16*)(ws + 201326592);
  f16*   X16  = (f16*)(ws + 201326592);   // overlaps cat; dead before k_attn writes cat
  f16*   qwT  = (f16*)(ws + 335544320);
  f16*   WcT  = (f16*)(ws + 337117184);
  float* bc   = (float*)(ws + 338165760);
  float* lbf  = (float*)(ws + 338167808);
  float* gbf  = (float*)(ws + 338429952);
  f16*   Kgb  = (f16*)(ws + 338692096);
  f16*   Vgt  = (f16*)(ws + 339740672);

  k_cvtx<<<2048, 256, 0, stream>>>(x, X16);
  k_biastab<<<32, 256, 0, stream>>>(ltab, gtab, lbf, gbf);
  k_tqkvw<<<192, 256, 0, stream>>>(qkv_w, qwT);
  k_compose<<<64, 256, 0, stream>>>(lpw, gpw, pfc_w, WcT);
  k_bc_init<<<2, 256, 0, stream>>>(pfc_b, bc);
  k_bc_acc<<<32, 256, 0, stream>>>(lpb, gpb, pfc_w, bc);
  k_gemm_qkv<<<3072, 512, 0, stream>>>(X16, qwT, qkv_b, qb, kb, vb);
  k_pool<<<16384, 64, 0, stream>>>(kb, vb, pool_w, pool_b, Kgb, Vgt);
  k_attn<<<16384, 256, 0, stream>>>(qb, kb, vb, Kgb, Vgt, lbf, gbf, cat);
  k_gemm_final<<<1024, 512, 0, stream>>>(cat, WcT, bc, out);
}